// Round 8
// baseline (676.751 us; speedup 1.0000x reference)
//
#include <hip/hip_runtime.h>
#include <hip/hip_bf16.h>
#include <stdint.h>

// GateProj: silu((qx @ dequant(W)^T) * qxscale + bias)
// M=4096 K=4096 N=14336 G=128. W int4 packed 8/int32, low nibble first.
//
// Round 12: round-11 occupancy experiment (2 independent 4-wave blocks/CU,
// BM=128 BN=256, 3x24KB LDS ring, chunk-pipelined lgkm) with the residency
// race FIXED: round 11 read tile kt+1 mid-body while its 6 staging loads
// were still in flight (3-ring retires them only at end-of-body). Now each
// body has two barriers: F = vmcnt+barrier BETWEEN the MFMA clusters
// (publishes tile kt+1 before its c0-prefetch reads), J = end-of-body
// barrier (seals the slot: its reads lgkm-drained at C and H, both < J).
// Ledger enumerated incl. prologue and kt=126/127 edges.

#define M_DIM 4096
#define K_DIM 4096
#define N_DIM 14336
#define GSZ   128

typedef __bf16 bf16x8 __attribute__((ext_vector_type(8)));
typedef __bf16 bf16x4 __attribute__((ext_vector_type(4)));
typedef float  f32x4  __attribute__((ext_vector_type(4)));

#define GLOAD16(g, l) __builtin_amdgcn_global_load_lds( \
    (const __attribute__((address_space(1))) void*)(g), \
    (__attribute__((address_space(3))) void*)(l), 16, 0, 0)

#define WAITVM(N) asm volatile("s_waitcnt vmcnt(" #N ")" ::: "memory")
#define WAITLGKM(N) asm volatile("s_waitcnt lgkmcnt(" #N ")" ::: "memory")
#define SB0() __builtin_amdgcn_sched_barrier(0)

// ---------------- prepass kernels ----------------

__global__ __launch_bounds__(256) void convertA_kernel(
    const float* __restrict__ qx, __bf16* __restrict__ out)
{
    const size_t i = ((size_t)blockIdx.x * 256 + threadIdx.x) * 8;
    const float4 a = *(const float4*)(qx + i);
    const float4 b = *(const float4*)(qx + i + 4);
    bf16x8 v;
    v[0] = (__bf16)a.x; v[1] = (__bf16)a.y; v[2] = (__bf16)a.z; v[3] = (__bf16)a.w;
    v[4] = (__bf16)b.x; v[5] = (__bf16)b.y; v[6] = (__bf16)b.z; v[7] = (__bf16)b.w;
    *(bf16x8*)(out + i) = v;
}

__global__ __launch_bounds__(256) void dequantW_kernel(
    const int* __restrict__ wq, const float* __restrict__ wscale,
    __bf16* __restrict__ out)
{
    const size_t g = (size_t)blockIdx.x * 256 + threadIdx.x;  // word index
    const int n  = (int)(g >> 9);                             // 512 words/row
    const int wi = (int)(g & 511);
    const float s = wscale[(size_t)n * (K_DIM / GSZ) + (wi >> 4)];
    const int w = wq[g];
    bf16x8 v;
    #pragma unroll
    for (int j = 0; j < 8; ++j) {
        const int q = ((int)((unsigned)w << (28 - 4 * j))) >> 28;
        v[j] = (__bf16)((float)q * s);
    }
    *(bf16x8*)(out + g * 8) = v;
}

// ---------------- main GEMM: 128x256, 4-wave blocks, 2 blocks/CU ----------

constexpr int BM = 128, BN = 256, BK = 32;
constexpr int NT = K_DIM / BK;          // 128
constexpr int SLOT = 24576;             // A 8KB + B 16KB per K-tile

__global__ __launch_bounds__(256, 2) void gemm128x256_kernel(
    const __bf16* __restrict__ A,       // [M,K] bf16
    const __bf16* __restrict__ B,       // [N,K] bf16
    const float* __restrict__ qxscale,  // [M]
    const float* __restrict__ bias,     // [N]
    float* __restrict__ out)            // [M,N]
{
    __shared__ __align__(16) char smem[3 * SLOT];   // 72 KiB -> 2 blocks/CU

    const int t    = threadIdx.x;       // 0..255
    const int lane = t & 63;
    const int wc   = t >> 6;            // wave 0..3 -> N quarter (64 cols)

    // XCD-bijective swizzle: nwg=1792 (32x56), 1792%8==0, m-major in chunk
    const int bid = blockIdx.x;
    const int cpx = (M_DIM / BM) * (N_DIM / BN) / 8;   // 224
    const int wg  = (bid & 7) * cpx + (bid >> 3);
    const int tiles_n = N_DIM / BN;                    // 56
    const int tm = wg / tiles_n, tn = wg % tiles_n;
    const int m0 = tm * BM, n0 = tn * BN;

    // --- staging: one sweep = 256 thr x 16B = 4KB = 64 rows x 64B.
    // Thread t: row srow = t>>2 (0..63), phys colbyte (t&3)*16; swizzle
    // field = row bits [2:1] = (t>>3)&3, applied to GLOBAL source (rule 21).
    // A = 2 sweeps (rows 0-63, 64-127); B = 4 sweeps (rows 0-255).
    const int srow = t >> 2;
    const int scb  = ((t & 3) * 16) ^ (((t >> 3) & 3) << 4);
    const size_t KB = (size_t)K_DIM * 2;
    const size_t sweepG = (size_t)64 * KB;             // 64 rows
    const char* aS = (const char*)A + (size_t)(m0 + srow) * KB + scb;
    const char* bS = (const char*)B + (size_t)(n0 + srow) * KB + scb;

    auto STAGE = [&](char* buf, int kt) {              // 6 gloads/thread
        const char* sa = aS + (size_t)kt * 64;
        char* d = buf + t * 16;
        GLOAD16(sa, d);
        GLOAD16(sa + sweepG, d + 4096);
        const char* sb = bS + (size_t)kt * 64;
        char* db = buf + 8192 + t * 16;
        GLOAD16(sb,              db);
        GLOAD16(sb + sweepG,     db + 4096);
        GLOAD16(sb + 2 * sweepG, db + 8192);
        GLOAD16(sb + 3 * sweepG, db + 12288);
    };

    // --- ds_read: row = R0 + lane15 (R0%16==0), phys byte col =
    // ((lane>>4)*16) ^ (((lane>>1)&3)<<4) (round-4/10 scheme, 0 conflicts).
    const int lane15 = lane & 15;
    const int pkb = ((lane >> 4) * 16) ^ (((lane >> 1) & 3) << 4);
    const int aRowB = lane15 * 64 + pkb;                      // + mi*1024
    const int bRowB = 8192 + (wc * 64 + lane15) * 64 + pkb;   // + ni*1024

    f32x4 acc[8][4] = {};
    bf16x8 afc[4], bfc[4];   // "cur" c0 set (af m0-3 + bf)
    bf16x8 afn[4], bfn[4];   // "next" c0 set
    bf16x8 af1[4];           // c1 set (af m4-7), reused every tile

    #define LA4(BUF, AF, BASE) do { _Pragma("unroll") \
        for (int i_ = 0; i_ < 4; ++i_) \
            AF[i_] = *(const bf16x8*)((BUF) + aRowB + ((BASE) + i_) * 1024); \
        } while (0)
    #define LB4(BUF, BF) do { _Pragma("unroll") \
        for (int n_ = 0; n_ < 4; ++n_) \
            BF[n_] = *(const bf16x8*)((BUF) + bRowB + n_ * 1024); \
        } while (0)
    #define MM16(AF, BF, AB) do { _Pragma("unroll") \
        for (int mi_ = 0; mi_ < 4; ++mi_) { _Pragma("unroll") \
            for (int ni_ = 0; ni_ < 4; ++ni_) \
                acc[(AB) + mi_][ni_] = __builtin_amdgcn_mfma_f32_16x16x32_bf16( \
                    AF[mi_], BF[ni_], acc[(AB) + mi_][ni_], 0, 0, 0); } \
        } while (0)

    char* p0 = smem;            // slot of even kt
    char* p1 = smem + SLOT;     // slot of odd kt
    char* p2 = smem + 2 * SLOT; // stage target for kt+2 (even body)

    // --- prologue: stage tiles 0,1 (12 gloads); retire tile0 (leave t1's 6);
    // barrier publishes t0; issue c0(0).
    STAGE(p0, 0);
    STAGE(p1, 1);
    WAITVM(6);
    __builtin_amdgcn_s_barrier();
    SB0();
    LA4(p0, afc, 0);
    LB4(p0, bfc);

    for (int it = 0; it < NT / 2; ++it) {
        // ============ even kt = 2*it: cur=p0 next=p1 stage=p2 =============
        {
            const int kt = 2 * it;
            if (kt + 2 < NT) STAGE(p2, kt + 2);       // 6 vm loads
            LA4(p0, af1, 4);                          // c1(kt): 4 ds
            WAITLGKM(4);                              // c0(kt) drained
            SB0();
            __builtin_amdgcn_s_setprio(1);
            MM16(afc, bfc, 0);                        // 16 MFMA; c1 in flight
            __builtin_amdgcn_s_setprio(0);
            // F: publish tile kt+1 BEFORE reading it (round-11 bug fix)
            if (kt + 2 < NT) WAITVM(6); else WAITVM(0);
            __builtin_amdgcn_s_barrier();
            SB0();
            LA4(p1, afn, 0);                          // c0(kt+1): 8 ds
            LB4(p1, bfn);
            WAITLGKM(8);                              // c1(kt) drained
            SB0();
            __builtin_amdgcn_s_setprio(1);
            MM16(af1, bfc, 4);                        // 16 MFMA; c0(kt+1) flows
            __builtin_amdgcn_s_setprio(0);
            // J: seal p0 (its reads drained at C and H above)
            __builtin_amdgcn_s_barrier();
            SB0();
        }
        // ============ odd kt = 2*it+1: cur=p1 next=p2 stage=p0 ============
        {
            const int kt = 2 * it + 1;
            if (kt + 2 < NT) STAGE(p0, kt + 2);
            LA4(p1, af1, 4);
            WAITLGKM(4);                              // c0(kt) drained
            SB0();
            __builtin_amdgcn_s_setprio(1);
            MM16(afn, bfn, 0);
            __builtin_amdgcn_s_setprio(0);
            if (kt + 1 < NT) {
                // F: publish tile kt+1
                if (kt + 2 < NT) WAITVM(6); else WAITVM(0);
                __builtin_amdgcn_s_barrier();
                SB0();
                LA4(p2, afc, 0);                      // c0(kt+1): 8 ds
                LB4(p2, bfc);
                WAITLGKM(8);                          // c1(kt) drained
            } else {
                WAITLGKM(0);                          // last tile: drain c1
            }
            SB0();
            __builtin_amdgcn_s_setprio(1);
            MM16(af1, bfn, 4);
            __builtin_amdgcn_s_setprio(0);
            if (kt + 1 < NT) {
                // J: seal p1
                __builtin_amdgcn_s_barrier();
                SB0();
            }
        }
        // rotate ring: next even kt uses old p2 as cur, old p0 as next,
        // old p1 as stage target
        char* tmp = p0; p0 = p2; p2 = p1; p1 = tmp;
    }

    #undef LA4
    #undef LB4
    #undef MM16

    // ---- epilogue: y = acc*qxscale[m] + bias[n]; silu ----
    // D layout: col = lane&15 (n), row = (lane>>4)*4 + reg (m)
    const int c_col = lane & 15;
    const int c_r4  = (lane >> 4) * 4;
    #pragma unroll
    for (int mi = 0; mi < 8; ++mi) {
        const int mg = m0 + mi * 16 + c_r4;
        float qs[4];
        #pragma unroll
        for (int r = 0; r < 4; ++r) qs[r] = qxscale[mg + r];
        #pragma unroll
        for (int ni = 0; ni < 4; ++ni) {
            const int ng = n0 + wc * 64 + ni * 16 + c_col;
            const float bv = bias[ng];
            #pragma unroll
            for (int r = 0; r < 4; ++r) {
                const float y = acc[mi][ni][r] * qs[r] + bv;
                out[(size_t)(mg + r) * N_DIM + ng] = y / (1.f + __expf(-y));
            }
        }
    }
}

// ---------------- fallback: round-1 fused kernel ----------------

constexpr int FBM = 128, FBN = 128, FBK = 64;
constexpr int FLDA = 72;

__global__ __launch_bounds__(256) void gateproj_fused_kernel(
    const float* __restrict__ qx, const float* __restrict__ qxscale,
    const int* __restrict__ wq, const float* __restrict__ wscale,
    const float* __restrict__ bias, float* __restrict__ out)
{
    __shared__ __bf16 sA[FBM * FLDA];
    __shared__ __bf16 sB[FBN * FLDA];

    const int tid  = threadIdx.x;
    const int lane = tid & 63;
    const int wave = tid >> 6;
    const int wm = wave >> 1, wn = wave & 1;

    const int bid = blockIdx.x;
    const int cpx = (M_DIM / FBM) * (N_DIM / FBN) / 8;
    const int wg  = (bid & 7) * cpx + (bid >> 3);
    const int tiles_n = N_DIM / FBN;
    const int tm = wg / tiles_n, tn = wg % tiles_n;
    const int m0 = tm * FBM, n0 = tn * FBN;

    const int a_row = tid >> 4;
    const int a_col = (tid & 15) * 4;
    const float* aPtr = qx + (size_t)(m0 + a_row) * K_DIM + a_col;

    const int b_row = tid >> 1;
    const int b_wb  = (tid & 1) * 4;
    const int*   bPtr = wq     + (size_t)(n0 + b_row) * (K_DIM / 8) + b_wb;
    const float* sPtr = wscale + (size_t)(n0 + b_row) * (K_DIM / GSZ);

    float4 aReg[8];
    int    bRegW[4];
    float  bScl;
    f32x4 acc[4][4] = {};

    auto LOAD = [&](int kt) {
        const float* ap = aPtr + kt * FBK;
        #pragma unroll
        for (int i = 0; i < 8; ++i)
            aReg[i] = *(const float4*)(ap + (size_t)i * 16 * K_DIM);
        int4 b = *(const int4*)(bPtr + kt * 8);
        bRegW[0] = b.x; bRegW[1] = b.y; bRegW[2] = b.z; bRegW[3] = b.w;
        bScl = sPtr[kt >> 1];
    };

    auto STORE = [&]() {
        #pragma unroll
        for (int i = 0; i < 8; ++i) {
            bf16x4 v;
            v[0] = (__bf16)aReg[i].x; v[1] = (__bf16)aReg[i].y;
            v[2] = (__bf16)aReg[i].z; v[3] = (__bf16)aReg[i].w;
            *(bf16x4*)&sA[(a_row + i * 16) * FLDA + a_col] = v;
        }
        const int cb = (tid & 1) * 32;
        #pragma unroll
        for (int wi = 0; wi < 4; ++wi) {
            const int w = bRegW[wi];
            bf16x8 o;
            #pragma unroll
            for (int j = 0; j < 8; ++j) {
                const int v = ((int)((unsigned)w << (28 - 4 * j))) >> 28;
                o[j] = (__bf16)((float)v * bScl);
            }
            *(bf16x8*)&sB[b_row * FLDA + cb + wi * 8] = o;
        }
    };

    LOAD(0); STORE(); __syncthreads();

    const int FNT = K_DIM / FBK;
    for (int kt = 0; kt < FNT; ++kt) {
        if (kt + 1 < FNT) LOAD(kt + 1);
        #pragma unroll
        for (int kk = 0; kk < 2; ++kk) {
            bf16x8 af2[4], bfr2[4];
            const int ko = kk * 32 + (lane >> 4) * 8;
            #pragma unroll
            for (int mi = 0; mi < 4; ++mi)
                af2[mi] = *(const bf16x8*)&sA[(wm * 64 + mi * 16 + (lane & 15)) * FLDA + ko];
            #pragma unroll
            for (int ni = 0; ni < 4; ++ni)
                bfr2[ni] = *(const bf16x8*)&sB[(wn * 64 + ni * 16 + (lane & 15)) * FLDA + ko];
            #pragma unroll
            for (int mi = 0; mi < 4; ++mi)
                #pragma unroll
                for (int ni = 0; ni < 4; ++ni)
                    acc[mi][ni] = __builtin_amdgcn_mfma_f32_16x16x32_bf16(
                        af2[mi], bfr2[ni], acc[mi][ni], 0, 0, 0);
        }
        __syncthreads();
        if (kt + 1 < FNT) { STORE(); __syncthreads(); }
    }

    const int c_col = lane & 15;
    const int c_r4  = (lane >> 4) * 4;
    #pragma unroll
    for (int mi = 0; mi < 4; ++mi) {
        const int mg = m0 + wm * 64 + mi * 16 + c_r4;
        float qs[4];
        #pragma unroll
        for (int r = 0; r < 4; ++r) qs[r] = qxscale[mg + r];
        #pragma unroll
        for (int ni = 0; ni < 4; ++ni) {
            const int ng = n0 + wn * 64 + ni * 16 + c_col;
            const float bv = bias[ng];
            #pragma unroll
            for (int r = 0; r < 4; ++r) {
                const float y = acc[mi][ni][r] * qs[r] + bv;
                out[(size_t)(mg + r) * N_DIM + ng] = y / (1.f + __expf(-y));
            }
        }
    }
}

// ---------------- launch ----------------

extern "C" void kernel_launch(void* const* d_in, const int* in_sizes, int n_in,
                              void* d_out, int out_size, void* d_ws, size_t ws_size,
                              hipStream_t stream) {
    const float* qx      = (const float*)d_in[0];
    const float* qxscale = (const float*)d_in[1];
    const int*   wq      = (const int*)d_in[2];
    const float* wscale  = (const float*)d_in[3];
    const float* bias    = (const float*)d_in[4];
    float* out = (float*)d_out;

    const size_t needA = (size_t)M_DIM * K_DIM * 2;
    const size_t needW = (size_t)N_DIM * K_DIM * 2;

    if (ws_size >= needA + needW) {
        __bf16* Abf = (__bf16*)d_ws;
        __bf16* Wbf = Abf + (size_t)M_DIM * K_DIM;

        hipLaunchKernelGGL(convertA_kernel, dim3(M_DIM * K_DIM / 8 / 256), dim3(256),
                           0, stream, qx, Abf);
        hipLaunchKernelGGL(dequantW_kernel, dim3(N_DIM * (K_DIM / 8) / 256), dim3(256),
                           0, stream, wq, wscale, Wbf);

        const int grid = (M_DIM / BM) * (N_DIM / BN);   // 1792
        hipLaunchKernelGGL(gemm128x256_kernel, dim3(grid), dim3(256), 0, stream,
                           Abf, Wbf, qxscale, bias, out);
    } else {
        const int grid = (M_DIM / FBM) * (N_DIM / FBN);
        hipLaunchKernelGGL(gateproj_fused_kernel, dim3(grid), dim3(256), 0, stream,
                           qx, qxscale, wq, wscale, bias, out);
    }
}

// Round 9
// 586.404 us; speedup vs baseline: 1.1541x; 1.1541x over previous
//
#include <hip/hip_runtime.h>
#include <hip/hip_bf16.h>
#include <stdint.h>

// GateProj: silu((qx @ dequant(W)^T) * qxscale + bias)
// M=4096 K=4096 N=14336 G=128. W int4 packed 8/int32, low nibble first.
//
// Round 13: fused int4-B GEMM on the round-10 chunk-pipeline skeleton.
// - W read RAW int4 in the GEMM (16B/row per BK=32 tile): kills the W
//   prepass (112MB wr+rd), cuts B fabric fetch 4x, B LDS reads 4x, B
//   staging 4x. A prepass converts f32->f16 (better than bf16).
// - In-register dequant to f16: x = nib_lo | nib_hi<<16; x ^= 0x64086408
//   (f16 pair 1024+(q^8)); pk_sub 1032 (exact signed int4); pk_mul s.
//   mfma_f32_16x16x32_f16 (same rate/layout as bf16).
// - Scales staged once to LDS transposed [g][n] (broadcast reads, 0
//   conflicts), read every tile for a uniform lgkm ledger (4/12).
// - vmcnt ledger (round-11 lesson: tile kt+1 retired+published at end of
//   body kt-1, before ANY mid-body read of kt+1): steady WAITVM(3)/(3);
//   tail peeled i=62 (2,0), i=63 (0, final body drains lgkm only).
// LDS: A-ring 4x16KB + B-pair-ring 3x8KB + scales 32KB = 120KB.

#define M_DIM 4096
#define K_DIM 4096
#define N_DIM 14336
#define GSZ   128

typedef _Float16 f16x8 __attribute__((ext_vector_type(8)));
typedef _Float16 h2    __attribute__((ext_vector_type(2)));
typedef float    f32x4 __attribute__((ext_vector_type(4)));
typedef unsigned int uint4v __attribute__((ext_vector_type(4)));
typedef __bf16 bf16x8 __attribute__((ext_vector_type(8)));
typedef __bf16 bf16x4 __attribute__((ext_vector_type(4)));

#define GLOAD16(g, l) __builtin_amdgcn_global_load_lds( \
    (const __attribute__((address_space(1))) void*)(g), \
    (__attribute__((address_space(3))) void*)(l), 16, 0, 0)

#define WAITVM_I(N) asm volatile("s_waitcnt vmcnt(" #N ")" ::: "memory")
#define WAITVM(N) WAITVM_I(N)
#define WAITLGKM_I(N) asm volatile("s_waitcnt lgkmcnt(" #N ")" ::: "memory")
#define WAITLGKM(N) WAITLGKM_I(N)
#define SB0() __builtin_amdgcn_sched_barrier(0)
#define PRIO1() __builtin_amdgcn_s_setprio(1)
#define PRIO0() __builtin_amdgcn_s_setprio(0)

// ---------------- prepass: A f32 -> f16 ----------------

__global__ __launch_bounds__(256) void convertA_kernel(
    const float* __restrict__ qx, _Float16* __restrict__ out)
{
    const size_t i = ((size_t)blockIdx.x * 256 + threadIdx.x) * 8;
    const float4 a = *(const float4*)(qx + i);
    const float4 b = *(const float4*)(qx + i + 4);
    f16x8 v;
    v[0] = (_Float16)a.x; v[1] = (_Float16)a.y;
    v[2] = (_Float16)a.z; v[3] = (_Float16)a.w;
    v[4] = (_Float16)b.x; v[5] = (_Float16)b.y;
    v[6] = (_Float16)b.z; v[7] = (_Float16)b.w;
    *(f16x8*)(out + i) = v;
}

// ---------------- fused int4-B GEMM ----------------

constexpr int BM = 256, BN = 256, BK = 32;
constexpr int NT = K_DIM / BK;          // 128 tiles, 64 iterations
constexpr int ASLOT = 16384;            // A: 256 rows x 64B
constexpr int A_RING = 0;               // 4 slots = 64KB
constexpr int BP_RING = 65536;          // 3 x 8KB pair slots = 24KB
constexpr int SCALES = 90112;           // [g 0..31][n 0..255] f32 = 32KB

static __device__ __forceinline__ f16x8 deq8(unsigned int w, float s) {
    _Float16 hs = (_Float16)s;
    unsigned short hb = __builtin_bit_cast(unsigned short, hs);
    unsigned int su = (unsigned int)hb | ((unsigned int)hb << 16);
    h2 s2 = __builtin_bit_cast(h2, su);
    const h2 kc = {(_Float16)1032.0f, (_Float16)1032.0f};
    unsigned int d0, d1, d2, d3;
    #define DQPAIR(J, D) { \
        unsigned int x = ((w >> (8*J)) & 0xFu) | (((w >> (8*J+4)) & 0xFu) << 16); \
        x ^= 0x64086408u; \
        h2 r = (__builtin_bit_cast(h2, x) - kc) * s2; \
        D = __builtin_bit_cast(unsigned int, r); }
    DQPAIR(0, d0) DQPAIR(1, d1) DQPAIR(2, d2) DQPAIR(3, d3)
    #undef DQPAIR
    uint4v u = {d0, d1, d2, d3};
    return __builtin_bit_cast(f16x8, u);
}

__global__ __launch_bounds__(512, 2) void gemm256_kernel(
    const _Float16* __restrict__ A,     // [M,K] f16 (workspace)
    const int* __restrict__ wq,         // [N, K/8] raw int4 words
    const float* __restrict__ wscale,   // [N, K/G]
    const float* __restrict__ qxscale,  // [M]
    const float* __restrict__ bias,     // [N]
    float* __restrict__ out)            // [M,N]
{
    __shared__ __align__(16) char smem[122880];

    const int t    = threadIdx.x;
    const int lane = t & 63;
    const int wave = t >> 6;
    const int wr   = wave >> 2;   // 0..1 -> M half (128 rows)
    const int wc   = wave & 3;    // 0..3 -> N quarter (64 cols)

    // XCD-bijective swizzle: nwg=896 (16x56), 896%8==0
    const int bid = blockIdx.x;
    const int cpx = (M_DIM / BM) * (N_DIM / BN) / 8;   // 112
    const int wg  = (bid & 7) * cpx + (bid >> 3);
    const int tiles_n = N_DIM / BN;                    // 56
    const int tm = wg / tiles_n, tn = wg % tiles_n;
    const int m0 = tm * BM, n0 = tn * BN;

    // --- A staging (round-10 verbatim; f16 has same 2B layout) ---
    const int srow = t >> 2;
    const int scb  = ((t & 3) * 16) ^ (((t >> 3) & 3) << 4);
    const char* aS = (const char*)A + (size_t)(m0 + srow) * K_DIM * 2 + scb;
    const size_t sweepG = (size_t)128 * K_DIM * 2;

    auto STAGE_A = [&](int kt) {
        char* d = smem + A_RING + (kt & 3) * ASLOT + t * 16;
        const char* s = aS + (size_t)kt * 64;
        GLOAD16(s, d);
        GLOAD16(s + sweepG, d + 8192);
    };
    // --- B pair staging: 8KB = tiles (2p, 2p+1); t<256 lo tile, t>=256 hi.
    const char* bpSrc = (const char*)wq
        + (size_t)(n0 + (t & 255)) * (K_DIM / 8 * 4)   // row bytes = 2048
        + (size_t)(t >> 8) * 16;
    auto STAGE_BP = [&](char* dst, int p) {
        GLOAD16(bpSrc + (size_t)p * 32, dst + t * 16);
    };

    // --- A ds_read addressing (round-10 verbatim, 0 conflicts) ---
    const int lane15 = lane & 15;
    const int pkb = ((lane >> 4) * 16) ^ (((lane >> 1) & 3) << 4);
    const int aRowB = (wr * 128 + lane15) * 64 + pkb;          // + mi*1024

    // --- B int4 read: b32 at row*16 + (lane>>4)*4 (2-way = free) ---
    const int bwOff = (wc * 64 + lane15) * 16 + ((lane >> 4) << 2);
    // --- scale read: [g][n] broadcast across lane-groups (free) ---
    const int sBase = SCALES + (wc * 64 + lane15) * 4;

    f32x4 acc[8][4] = {};
    f16x8 afc[4], afn[4], af1[4];   // A frags (double c0 set + c1)
    f16x8 bf[4];                    // dequantized B frags (single set)
    unsigned int bw[4];             // raw int4 words for next tile
    float srf[4];                   // scales for next tile

    #define LA4(BUF, AF, BASE) do { _Pragma("unroll") \
        for (int i_ = 0; i_ < 4; ++i_) \
            AF[i_] = *(const f16x8*)((BUF) + aRowB + ((BASE) + i_) * 1024); \
        } while (0)
    #define LBW4(P) do { _Pragma("unroll") \
        for (int n_ = 0; n_ < 4; ++n_) \
            bw[n_] = *(const unsigned int*)((P) + bwOff + n_ * 256); \
        } while (0)
    #define LSR4(G) do { _Pragma("unroll") \
        for (int n_ = 0; n_ < 4; ++n_) \
            srf[n_] = *(const float*)(smem + sBase + (G) * 1024 + n_ * 64); \
        } while (0)
    #define DEQ4() do { _Pragma("unroll") \
        for (int n_ = 0; n_ < 4; ++n_) bf[n_] = deq8(bw[n_], srf[n_]); \
        } while (0)
    #define MM16(AF, AB) do { _Pragma("unroll") \
        for (int mi_ = 0; mi_ < 4; ++mi_) { _Pragma("unroll") \
            for (int ni_ = 0; ni_ < 4; ++ni_) \
                acc[(AB) + mi_][ni_] = __builtin_amdgcn_mfma_f32_16x16x32_f16( \
                    AF[mi_], bf[ni_], acc[(AB) + mi_][ni_], 0, 0, 0); } \
        } while (0)

    char* bpCur   = smem + BP_RING;            // pair i
    char* bpNext  = smem + BP_RING + 8192;     // pair i+1
    char* bpStage = smem + BP_RING + 16384;    // stage target pair i+2

    // --- prologue: scales -> LDS transposed [g][n] ---
    {
        const float* wsp = wscale + (size_t)n0 * (K_DIM / GSZ);
        #pragma unroll
        for (int j = 0; j < 16; ++j) {
            const int slot = t * 16 + j;                 // g*256 + n
            const float v = wsp[(size_t)(slot & 255) * (K_DIM / GSZ) + (slot >> 8)];
            *(float*)(smem + SCALES + slot * 4) = v;
        }
    }
    // stage A(0..2), BP(0..1); FIFO [A0ab BP0 A1ab BP1 A2ab]; retire thru A1b
    STAGE_A(0);
    STAGE_BP(bpCur, 0);
    STAGE_A(1);
    STAGE_BP(bpNext, 1);
    STAGE_A(2);
    WAITVM(3);
    WAITLGKM(0);                 // drain scale ds_writes before publishing
    __builtin_amdgcn_s_barrier();
    SB0();
    // c0(0): afc + bw/s for tile 0 (12 lgkm ops)
    LA4(smem + A_RING, afc, 0);
    LBW4(bpCur);
    LSR4(0);

    // body for tile KT. CUR = c0 A-frag set for KT; NXT loaded for KT+1.
    // BPNXT = LDS base of tile KT+1's int4 words.
    #define KBODY(KT, CUR, NXT, BPNXT, STAGE_STMTS, VMN) { \
        LA4(smem + A_RING + ((KT) & 3) * ASLOT, af1, 4); \
        STAGE_STMTS \
        WAITLGKM(4); SB0(); \
        DEQ4(); \
        PRIO1(); MM16(CUR, 0); PRIO0(); \
        LA4(smem + A_RING + (((KT) + 1) & 3) * ASLOT, NXT, 0); \
        LBW4(BPNXT); \
        LSR4(((KT) + 1) >> 2); \
        WAITLGKM(12); SB0(); \
        PRIO1(); MM16(af1, 4); PRIO0(); \
        WAITVM(VMN); \
        __builtin_amdgcn_s_barrier(); SB0(); }

    for (int i = 0; i < 62; ++i) {
        const int kt0 = 2 * i;
        KBODY(kt0, afc, afn, bpCur + 4096,
              { STAGE_A(kt0 + 3); STAGE_BP(bpStage, i + 2); }, 3)
        KBODY(kt0 + 1, afn, afc, bpNext,
              { STAGE_A(kt0 + 4); }, 3)
        char* tmp = bpCur; bpCur = bpNext; bpNext = bpStage; bpStage = tmp;
    }
    // i = 62 (tiles 124, 125): stage only A(127); vm tail 2, 0
    KBODY(124, afc, afn, bpCur + 4096, { STAGE_A(127); }, 2)
    KBODY(125, afn, afc, bpNext, { }, 0)
    { char* tmp = bpCur; bpCur = bpNext; bpNext = bpStage; bpStage = tmp; }
    // i = 63 (tiles 126, 127)
    KBODY(126, afc, afn, bpCur + 4096, { }, 0)
    // final body, tile 127: no next-c0
    {
        LA4(smem + A_RING + (127 & 3) * ASLOT, af1, 4);
        WAITLGKM(4); SB0();
        DEQ4();
        PRIO1(); MM16(afn, 0); PRIO0();
        WAITLGKM(0); SB0();
        PRIO1(); MM16(af1, 4); PRIO0();
    }

    #undef KBODY
    #undef LA4
    #undef LBW4
    #undef LSR4
    #undef DEQ4
    #undef MM16

    // ---- epilogue: y = acc*qxscale[m] + bias[n]; silu ----
    // D layout: col = lane&15 (n), row = (lane>>4)*4 + reg (m)
    const int c_col = lane & 15;
    const int c_r4  = (lane >> 4) * 4;
    #pragma unroll
    for (int mi = 0; mi < 8; ++mi) {
        const int mg = m0 + wr * 128 + mi * 16 + c_r4;
        float qs[4];
        #pragma unroll
        for (int r = 0; r < 4; ++r) qs[r] = qxscale[mg + r];
        #pragma unroll
        for (int ni = 0; ni < 4; ++ni) {
            const int ng = n0 + wc * 64 + ni * 16 + c_col;
            const float bv = bias[ng];
            #pragma unroll
            for (int r = 0; r < 4; ++r) {
                const float y = acc[mi][ni][r] * qs[r] + bv;
                out[(size_t)(mg + r) * N_DIM + ng] = y / (1.f + __expf(-y));
            }
        }
    }
}

// ---------------- fallback: round-1 fused kernel (bf16) ----------------

constexpr int FBM = 128, FBN = 128, FBK = 64;
constexpr int FLDA = 72;

__global__ __launch_bounds__(256) void gateproj_fused_kernel(
    const float* __restrict__ qx, const float* __restrict__ qxscale,
    const int* __restrict__ wq, const float* __restrict__ wscale,
    const float* __restrict__ bias, float* __restrict__ out)
{
    __shared__ __bf16 sA[FBM * FLDA];
    __shared__ __bf16 sB[FBN * FLDA];

    const int tid  = threadIdx.x;
    const int lane = tid & 63;
    const int wave = tid >> 6;
    const int wm = wave >> 1, wn = wave & 1;

    const int bid = blockIdx.x;
    const int cpx = (M_DIM / FBM) * (N_DIM / FBN) / 8;
    const int wg  = (bid & 7) * cpx + (bid >> 3);
    const int tiles_n = N_DIM / FBN;
    const int tm = wg / tiles_n, tn = wg % tiles_n;
    const int m0 = tm * FBM, n0 = tn * FBN;

    const int a_row = tid >> 4;
    const int a_col = (tid & 15) * 4;
    const float* aPtr = qx + (size_t)(m0 + a_row) * K_DIM + a_col;

    const int b_row = tid >> 1;
    const int b_wb  = (tid & 1) * 4;
    const int*   bPtr = wq     + (size_t)(n0 + b_row) * (K_DIM / 8) + b_wb;
    const float* sPtr = wscale + (size_t)(n0 + b_row) * (K_DIM / GSZ);

    float4 aReg[8];
    int    bRegW[4];
    float  bScl;
    f32x4 acc[4][4] = {};

    auto LOAD = [&](int kt) {
        const float* ap = aPtr + kt * FBK;
        #pragma unroll
        for (int i = 0; i < 8; ++i)
            aReg[i] = *(const float4*)(ap + (size_t)i * 16 * K_DIM);
        int4 b = *(const int4*)(bPtr + kt * 8);
        bRegW[0] = b.x; bRegW[1] = b.y; bRegW[2] = b.z; bRegW[3] = b.w;
        bScl = sPtr[kt >> 1];
    };

    auto STORE = [&]() {
        #pragma unroll
        for (int i = 0; i < 8; ++i) {
            bf16x4 v;
            v[0] = (__bf16)aReg[i].x; v[1] = (__bf16)aReg[i].y;
            v[2] = (__bf16)aReg[i].z; v[3] = (__bf16)aReg[i].w;
            *(bf16x4*)&sA[(a_row + i * 16) * FLDA + a_col] = v;
        }
        const int cb = (tid & 1) * 32;
        #pragma unroll
        for (int wi = 0; wi < 4; ++wi) {
            const int w = bRegW[wi];
            bf16x8 o;
            #pragma unroll
            for (int j = 0; j < 8; ++j) {
                const int v = ((int)((unsigned)w << (28 - 4 * j))) >> 28;
                o[j] = (__bf16)((float)v * bScl);
            }
            *(bf16x8*)&sB[b_row * FLDA + cb + wi * 8] = o;
        }
    };

    LOAD(0); STORE(); __syncthreads();

    const int FNT = K_DIM / FBK;
    for (int kt = 0; kt < FNT; ++kt) {
        if (kt + 1 < FNT) LOAD(kt + 1);
        #pragma unroll
        for (int kk = 0; kk < 2; ++kk) {
            bf16x8 af2[4], bfr2[4];
            const int ko = kk * 32 + (lane >> 4) * 8;
            #pragma unroll
            for (int mi = 0; mi < 4; ++mi)
                af2[mi] = *(const bf16x8*)&sA[(wm * 64 + mi * 16 + (lane & 15)) * FLDA + ko];
            #pragma unroll
            for (int ni = 0; ni < 4; ++ni)
                bfr2[ni] = *(const bf16x8*)&sB[(wn * 64 + ni * 16 + (lane & 15)) * FLDA + ko];
            #pragma unroll
            for (int mi = 0; mi < 4; ++mi)
                #pragma unroll
                for (int ni = 0; ni < 4; ++ni)
                    acc[mi][ni] = __builtin_amdgcn_mfma_f32_16x16x32_bf16(
                        af2[mi], bfr2[ni], acc[mi][ni], 0, 0, 0);
        }
        __syncthreads();
        if (kt + 1 < FNT) { STORE(); __syncthreads(); }
    }

    const int c_col = lane & 15;
    const int c_r4  = (lane >> 4) * 4;
    #pragma unroll
    for (int mi = 0; mi < 4; ++mi) {
        const int mg = m0 + wm * 64 + mi * 16 + c_r4;
        float qs[4];
        #pragma unroll
        for (int r = 0; r < 4; ++r) qs[r] = qxscale[mg + r];
        #pragma unroll
        for (int ni = 0; ni < 4; ++ni) {
            const int ng = n0 + wn * 64 + ni * 16 + c_col;
            const float bv = bias[ng];
            #pragma unroll
            for (int r = 0; r < 4; ++r) {
                const float y = acc[mi][ni][r] * qs[r] + bv;
                out[(size_t)(mg + r) * N_DIM + ng] = y / (1.f + __expf(-y));
            }
        }
    }
}

// ---------------- launch ----------------

extern "C" void kernel_launch(void* const* d_in, const int* in_sizes, int n_in,
                              void* d_out, int out_size, void* d_ws, size_t ws_size,
                              hipStream_t stream) {
    const float* qx      = (const float*)d_in[0];
    const float* qxscale = (const float*)d_in[1];
    const int*   wq      = (const int*)d_in[2];
    const float* wscale  = (const float*)d_in[3];
    const float* bias    = (const float*)d_in[4];
    float* out = (float*)d_out;

    const size_t needA = (size_t)M_DIM * K_DIM * 2;   // f16 A only

    if (ws_size >= needA) {
        _Float16* Ah = (_Float16*)d_ws;

        hipLaunchKernelGGL(convertA_kernel, dim3(M_DIM * K_DIM / 8 / 256), dim3(256),
                           0, stream, qx, Ah);

        const int grid = (M_DIM / BM) * (N_DIM / BN);   // 896
        hipLaunchKernelGGL(gemm256_kernel, dim3(grid), dim3(512), 0, stream,
                           Ah, wq, wscale, qxscale, bias, out);
    } else {
        const int grid = (M_DIM / FBM) * (N_DIM / FBN);
        hipLaunchKernelGGL(gateproj_fused_kernel, dim3(grid), dim3(256), 0, stream,
                           qx, qxscale, wq, wscale, bias, out);
    }
}

// Round 10
// 528.693 us; speedup vs baseline: 1.2800x; 1.1092x over previous
//
#include <hip/hip_runtime.h>
#include <hip/hip_bf16.h>
#include <stdint.h>

// GateProj: silu((qx @ dequant(W)^T) * qxscale + bias)
// M=4096 K=4096 N=14336 G=128. W int4 packed 8/int32, low nibble first.
//
// Round 14: round-10 kernel (best, GEMM 494us) with the grid tail fixed.
// 896 blocks = 3.5 block-waves wasted 12.5% makespan (128 CUs half-idle).
// New tile 256x224 -> grid 16x64 = 1024 = 4.0 EXACT block-waves. 8 waves
// as 4x2, per-wave 64x112 (acc[4][7]=112 AGPR; intensity 41.7K vs round-10
// 43.7K FLOP/ds_read, -5%). Chunk pipeline, swizzle, ring-4, stage D=3,
// counted vmcnt all round-10 verbatim (recounted: 6 gloads/tile ->
// steady WAITVM(6); B staged as GLOAD16 (rows 0-127) + 3x GLOAD4
// (rows 128-223) for a uniform per-wave ledger).

#define M_DIM 4096
#define K_DIM 4096
#define N_DIM 14336
#define GSZ   128

typedef __bf16 bf16x8 __attribute__((ext_vector_type(8)));
typedef __bf16 bf16x4 __attribute__((ext_vector_type(4)));
typedef float  f32x4  __attribute__((ext_vector_type(4)));

#define GLOAD16(g, l) __builtin_amdgcn_global_load_lds( \
    (const __attribute__((address_space(1))) void*)(g), \
    (__attribute__((address_space(3))) void*)(l), 16, 0, 0)
#define GLOAD4(g, l) __builtin_amdgcn_global_load_lds( \
    (const __attribute__((address_space(1))) void*)(g), \
    (__attribute__((address_space(3))) void*)(l), 4, 0, 0)

#define WAITVM(N) asm volatile("s_waitcnt vmcnt(" #N ")" ::: "memory")
#define WAITLGKM(N) asm volatile("s_waitcnt lgkmcnt(" #N ")" ::: "memory")
#define SB0() __builtin_amdgcn_sched_barrier(0)
#define PRIO1() __builtin_amdgcn_s_setprio(1)
#define PRIO0() __builtin_amdgcn_s_setprio(0)

// ---------------- prepass kernels (round-10 verbatim) ----------------

__global__ __launch_bounds__(256) void convertA_kernel(
    const float* __restrict__ qx, __bf16* __restrict__ out)
{
    const size_t i = ((size_t)blockIdx.x * 256 + threadIdx.x) * 8;
    const float4 a = *(const float4*)(qx + i);
    const float4 b = *(const float4*)(qx + i + 4);
    bf16x8 v;
    v[0] = (__bf16)a.x; v[1] = (__bf16)a.y; v[2] = (__bf16)a.z; v[3] = (__bf16)a.w;
    v[4] = (__bf16)b.x; v[5] = (__bf16)b.y; v[6] = (__bf16)b.z; v[7] = (__bf16)b.w;
    *(bf16x8*)(out + i) = v;
}

__global__ __launch_bounds__(256) void dequantW_kernel(
    const int* __restrict__ wq, const float* __restrict__ wscale,
    __bf16* __restrict__ out)
{
    const size_t g = (size_t)blockIdx.x * 256 + threadIdx.x;  // word index
    const int n  = (int)(g >> 9);                             // 512 words/row
    const int wi = (int)(g & 511);
    const float s = wscale[(size_t)n * (K_DIM / GSZ) + (wi >> 4)];
    const int w = wq[g];
    bf16x8 v;
    #pragma unroll
    for (int j = 0; j < 8; ++j) {
        const int q = ((int)((unsigned)w << (28 - 4 * j))) >> 28;
        v[j] = (__bf16)((float)q * s);
    }
    *(bf16x8*)(out + g * 8) = v;
}

// ---------------- main GEMM: 256x224, 4.0 exact block-waves ----------------

constexpr int BM = 256, BN = 224, BK = 32;
constexpr int NT = K_DIM / BK;          // 128
constexpr int SLOT = 30720;             // A 16KB + B 14KB per K-tile

__global__ __launch_bounds__(512, 2) void gemm224_kernel(
    const __bf16* __restrict__ A,       // [M,K] bf16
    const __bf16* __restrict__ B,       // [N,K] bf16
    const float* __restrict__ qxscale,  // [M]
    const float* __restrict__ bias,     // [N]
    float* __restrict__ out)            // [M,N]
{
    __shared__ __align__(16) char smem[4 * SLOT];   // 120 KiB, 4-deep ring

    const int t    = threadIdx.x;
    const int lane = t & 63;
    const int wave = t >> 6;
    const int wr   = wave >> 1;   // 0..3 -> M quarter (64 rows)
    const int wc   = wave & 1;    // 0..1 -> N half (112 cols)

    // XCD-bijective swizzle: nwg=1024 (16x64), 1024%8==0, m-major in chunk
    const int bid = blockIdx.x;
    const int cpx = (M_DIM / BM) * (N_DIM / BN) / 8;   // 128
    const int wg  = (bid & 7) * cpx + (bid >> 3);
    const int tiles_n = N_DIM / BN;                    // 64
    const int tm = wg / tiles_n, tn = wg % tiles_n;
    const int m0 = tm * BM, n0 = tn * BN;

    // --- staging (round-10 swizzle: phys granule ^= row bits [2:1]) ---
    // 16B sweeps: thread t -> row t>>2, granule (t&3) ^ ((t>>3)&3).
    const int srow = t >> 2;
    const int scb  = ((t & 3) * 16) ^ (((t >> 3) & 3) << 4);
    const size_t KB = (size_t)K_DIM * 2;
    const size_t sweepG = (size_t)128 * KB;            // 128 rows
    const char* aS = (const char*)A + (size_t)(m0 + srow) * KB + scb;
    const char* bS = (const char*)B + (size_t)(n0 + srow) * KB + scb;
    // 4B sweeps (B rows 128-223, 32 rows each): thread t -> row 128+(t>>4),
    // granule (t&15)>>2 ^ ((t>>5)&3), byte-in-granule (t&3)*4.
    const int g4 = ((((t & 15) >> 2) ^ ((t >> 5) & 3)) << 4) + (t & 3) * 4;
    const char* bS4 = (const char*)B + (size_t)(n0 + 128 + (t >> 4)) * KB + g4;

    auto STAGE = [&](int kt) {                         // 6 gloads/thread
        char* slot = smem + (kt & 3) * SLOT;
        const char* sa = aS + (size_t)kt * 64;
        GLOAD16(sa,           slot + t * 16);          // A rows 0-127
        GLOAD16(sa + sweepG,  slot + 8192 + t * 16);   // A rows 128-255
        const char* sb = bS + (size_t)kt * 64;
        GLOAD16(sb,           slot + 16384 + t * 16);  // B rows 0-127
        const char* sb4 = bS4 + (size_t)kt * 64;
        GLOAD4(sb4,               slot + 24576 + t * 4);          // B 128-159
        GLOAD4(sb4 + 32 * KB,     slot + 24576 + 2048 + t * 4);   // B 160-191
        GLOAD4(sb4 + 64 * KB,     slot + 24576 + 4096 + t * 4);   // B 192-223
    };

    // --- ds_read: row = R0 + lane15 (R0 % 16 == 0 -> same pkb as round 10,
    // measured 0 conflicts) ---
    const int lane15 = lane & 15;
    const int pkb = ((lane >> 4) * 16) ^ (((lane >> 1) & 3) << 4);
    const int aRowB = (wr * 64 + lane15) * 64 + pkb;              // + mi*1024
    const int bRowB = 16384 + (wc * 112 + lane15) * 64 + pkb;     // + ni*1024

    f32x4 acc[4][7] = {};
    bf16x8 afc[4], bfc[4];   // "cur" c0 set (A m0-3 + B n0-3)
    bf16x8 afn[4], bfn[4];   // "next" c0 set
    bf16x8 bf1[3];           // c1 set (B n4-6), reused every tile

    #define LA4(SLOTP, AF) do { _Pragma("unroll") \
        for (int i_ = 0; i_ < 4; ++i_) \
            AF[i_] = *(const bf16x8*)((SLOTP) + aRowB + i_ * 1024); \
        } while (0)
    #define LB4(SLOTP, BF) do { _Pragma("unroll") \
        for (int n_ = 0; n_ < 4; ++n_) \
            BF[n_] = *(const bf16x8*)((SLOTP) + bRowB + n_ * 1024); \
        } while (0)
    #define LB3(SLOTP) do { _Pragma("unroll") \
        for (int n_ = 0; n_ < 3; ++n_) \
            bf1[n_] = *(const bf16x8*)((SLOTP) + bRowB + (4 + n_) * 1024); \
        } while (0)
    #define MMC0(AF, BF) do { _Pragma("unroll") \
        for (int mi_ = 0; mi_ < 4; ++mi_) { _Pragma("unroll") \
            for (int ni_ = 0; ni_ < 4; ++ni_) \
                acc[mi_][ni_] = __builtin_amdgcn_mfma_f32_16x16x32_bf16( \
                    AF[mi_], BF[ni_], acc[mi_][ni_], 0, 0, 0); } \
        } while (0)
    #define MMC1(AF) do { _Pragma("unroll") \
        for (int mi_ = 0; mi_ < 4; ++mi_) { _Pragma("unroll") \
            for (int ni_ = 0; ni_ < 3; ++ni_) \
                acc[mi_][4 + ni_] = __builtin_amdgcn_mfma_f32_16x16x32_bf16( \
                    AF[mi_], bf1[ni_], acc[mi_][4 + ni_], 0, 0, 0); } \
        } while (0)

    // body kt: {c1 reads, stage kt+3, lgkm(3), 16 MFMA, next-c0 reads,
    // lgkm(8), 12 MFMA, counted vmcnt, barrier}. Publication invariant
    // (round-11 lesson): WAITVM at end of body kt retires through tile kt+2
    // (read as c0-ahead in body kt+1) -> steady WAITVM(6), leaves kt+3.
    #define KBODY(KT, AFC, BFC, AFN, BFN) { \
        const char* cur = smem + ((KT) & 3) * SLOT; \
        const char* nxt = smem + (((KT) + 1) & 3) * SLOT; \
        LB3(cur); \
        if ((KT) + 3 < NT) STAGE((KT) + 3); \
        WAITLGKM(3); SB0(); \
        PRIO1(); MMC0(AFC, BFC); PRIO0(); \
        LA4(nxt, AFN); LB4(nxt, BFN); \
        WAITLGKM(8); SB0(); \
        PRIO1(); MMC1(AFC); PRIO0(); \
        if ((KT) + 3 < NT) WAITVM(6); else WAITVM(0); \
        __builtin_amdgcn_s_barrier(); SB0(); }

    // --- prologue: stage tiles 0,1,2 (18 gloads); publish 0,1 (leave 2);
    // issue c0(0) -> entry state matches steady (8 lgkm outstanding).
    STAGE(0);
    STAGE(1);
    STAGE(2);
    WAITVM(6);
    __builtin_amdgcn_s_barrier();
    SB0();
    LA4(smem, afc);
    LB4(smem, bfc);

    for (int i = 0; i < 63; ++i) {
        const int kt = 2 * i;
        KBODY(kt,     afc, bfc, afn, bfn)
        KBODY(kt + 1, afn, bfn, afc, bfc)
    }
    // body 126 (loads c0(127) into afn/bfn; no stage; drain vm)
    KBODY(126, afc, bfc, afn, bfn)
    // body 127 (final: no next-c0, drain lgkm)
    {
        const char* cur = smem + (127 & 3) * SLOT;
        LB3(cur);
        WAITLGKM(3); SB0();
        PRIO1(); MMC0(afn, bfn); PRIO0();
        WAITLGKM(0); SB0();
        PRIO1(); MMC1(afn); PRIO0();
    }

    #undef KBODY
    #undef LA4
    #undef LB4
    #undef LB3
    #undef MMC0
    #undef MMC1

    // ---- epilogue: y = acc*qxscale[m] + bias[n]; silu ----
    // D layout: col = lane&15 (n), row = (lane>>4)*4 + reg (m)
    const int c_col = lane & 15;
    const int c_r4  = (lane >> 4) * 4;
    #pragma unroll
    for (int mi = 0; mi < 4; ++mi) {
        const int mg = m0 + wr * 64 + mi * 16 + c_r4;
        float qs[4];
        #pragma unroll
        for (int r = 0; r < 4; ++r) qs[r] = qxscale[mg + r];
        #pragma unroll
        for (int ni = 0; ni < 7; ++ni) {
            const int ng = n0 + wc * 112 + ni * 16 + c_col;
            const float bv = bias[ng];
            #pragma unroll
            for (int r = 0; r < 4; ++r) {
                const float y = acc[mi][ni][r] * qs[r] + bv;
                out[(size_t)(mg + r) * N_DIM + ng] = y / (1.f + __expf(-y));
            }
        }
    }
}

// ---------------- fallback: round-1 fused kernel ----------------

constexpr int FBM = 128, FBN = 128, FBK = 64;
constexpr int FLDA = 72;

__global__ __launch_bounds__(256) void gateproj_fused_kernel(
    const float* __restrict__ qx, const float* __restrict__ qxscale,
    const int* __restrict__ wq, const float* __restrict__ wscale,
    const float* __restrict__ bias, float* __restrict__ out)
{
    __shared__ __bf16 sA[FBM * FLDA];
    __shared__ __bf16 sB[FBN * FLDA];

    const int tid  = threadIdx.x;
    const int lane = tid & 63;
    const int wave = tid >> 6;
    const int wm = wave >> 1, wn = wave & 1;

    const int bid = blockIdx.x;
    const int cpx = (M_DIM / FBM) * (N_DIM / FBN) / 8;
    const int wg  = (bid & 7) * cpx + (bid >> 3);
    const int tiles_n = N_DIM / FBN;
    const int tm = wg / tiles_n, tn = wg % tiles_n;
    const int m0 = tm * FBM, n0 = tn * FBN;

    const int a_row = tid >> 4;
    const int a_col = (tid & 15) * 4;
    const float* aPtr = qx + (size_t)(m0 + a_row) * K_DIM + a_col;

    const int b_row = tid >> 1;
    const int b_wb  = (tid & 1) * 4;
    const int*   bPtr = wq     + (size_t)(n0 + b_row) * (K_DIM / 8) + b_wb;
    const float* sPtr = wscale + (size_t)(n0 + b_row) * (K_DIM / GSZ);

    float4 aReg[8];
    int    bRegW[4];
    float  bScl;
    f32x4 acc[4][4] = {};

    auto LOAD = [&](int kt) {
        const float* ap = aPtr + kt * FBK;
        #pragma unroll
        for (int i = 0; i < 8; ++i)
            aReg[i] = *(const float4*)(ap + (size_t)i * 16 * K_DIM);
        int4 b = *(const int4*)(bPtr + kt * 8);
        bRegW[0] = b.x; bRegW[1] = b.y; bRegW[2] = b.z; bRegW[3] = b.w;
        bScl = sPtr[kt >> 1];
    };

    auto STORE = [&]() {
        #pragma unroll
        for (int i = 0; i < 8; ++i) {
            bf16x4 v;
            v[0] = (__bf16)aReg[i].x; v[1] = (__bf16)aReg[i].y;
            v[2] = (__bf16)aReg[i].z; v[3] = (__bf16)aReg[i].w;
            *(bf16x4*)&sA[(a_row + i * 16) * FLDA + a_col] = v;
        }
        const int cb = (tid & 1) * 32;
        #pragma unroll
        for (int wi = 0; wi < 4; ++wi) {
            const int w = bRegW[wi];
            bf16x8 o;
            #pragma unroll
            for (int j = 0; j < 8; ++j) {
                const int v = ((int)((unsigned)w << (28 - 4 * j))) >> 28;
                o[j] = (__bf16)((float)v * bScl);
            }
            *(bf16x8*)&sB[b_row * FLDA + cb + wi * 8] = o;
        }
    };

    LOAD(0); STORE(); __syncthreads();

    const int FNT = K_DIM / FBK;
    for (int kt = 0; kt < FNT; ++kt) {
        if (kt + 1 < FNT) LOAD(kt + 1);
        #pragma unroll
        for (int kk = 0; kk < 2; ++kk) {
            bf16x8 af2[4], bfr2[4];
            const int ko = kk * 32 + (lane >> 4) * 8;
            #pragma unroll
            for (int mi = 0; mi < 4; ++mi)
                af2[mi] = *(const bf16x8*)&sA[(wm * 64 + mi * 16 + (lane & 15)) * FLDA + ko];
            #pragma unroll
            for (int ni = 0; ni < 4; ++ni)
                bfr2[ni] = *(const bf16x8*)&sB[(wn * 64 + ni * 16 + (lane & 15)) * FLDA + ko];
            #pragma unroll
            for (int mi = 0; mi < 4; ++mi)
                #pragma unroll
                for (int ni = 0; ni < 4; ++ni)
                    acc[mi][ni] = __builtin_amdgcn_mfma_f32_16x16x32_bf16(
                        af2[mi], bfr2[ni], acc[mi][ni], 0, 0, 0);
        }
        __syncthreads();
        if (kt + 1 < FNT) { STORE(); __syncthreads(); }
    }

    const int c_col = lane & 15;
    const int c_r4  = (lane >> 4) * 4;
    #pragma unroll
    for (int mi = 0; mi < 4; ++mi) {
        const int mg = m0 + wm * 64 + mi * 16 + c_r4;
        float qs[4];
        #pragma unroll
        for (int r = 0; r < 4; ++r) qs[r] = qxscale[mg + r];
        #pragma unroll
        for (int ni = 0; ni < 4; ++ni) {
            const int ng = n0 + wn * 64 + ni * 16 + c_col;
            const float bv = bias[ng];
            #pragma unroll
            for (int r = 0; r < 4; ++r) {
                const float y = acc[mi][ni][r] * qs[r] + bv;
                out[(size_t)(mg + r) * N_DIM + ng] = y / (1.f + __expf(-y));
            }
        }
    }
}

// ---------------- launch ----------------

extern "C" void kernel_launch(void* const* d_in, const int* in_sizes, int n_in,
                              void* d_out, int out_size, void* d_ws, size_t ws_size,
                              hipStream_t stream) {
    const float* qx      = (const float*)d_in[0];
    const float* qxscale = (const float*)d_in[1];
    const int*   wq      = (const int*)d_in[2];
    const float* wscale  = (const float*)d_in[3];
    const float* bias    = (const float*)d_in[4];
    float* out = (float*)d_out;

    const size_t needA = (size_t)M_DIM * K_DIM * 2;
    const size_t needW = (size_t)N_DIM * K_DIM * 2;

    if (ws_size >= needA + needW) {
        __bf16* Abf = (__bf16*)d_ws;
        __bf16* Wbf = Abf + (size_t)M_DIM * K_DIM;

        hipLaunchKernelGGL(convertA_kernel, dim3(M_DIM * K_DIM / 8 / 256), dim3(256),
                           0, stream, qx, Abf);
        hipLaunchKernelGGL(dequantW_kernel, dim3(N_DIM * (K_DIM / 8) / 256), dim3(256),
                           0, stream, wq, wscale, Wbf);

        const int grid = (M_DIM / BM) * (N_DIM / BN);   // 1024
        hipLaunchKernelGGL(gemm224_kernel, dim3(grid), dim3(512), 0, stream,
                           Abf, Wbf, qxscale, bias, out);
    } else {
        const int grid = (M_DIM / FBM) * (N_DIM / FBN);
        hipLaunchKernelGGL(gateproj_fused_kernel, dim3(grid), dim3(256), 0, stream,
                           qx, qxscale, wq, wscale, bias, out);
    }
}